// Round 2
// baseline (1012.948 us; speedup 1.0000x reference)
//
#include <hip/hip_runtime.h>

#define NMUL 16
#define NSTEP 365
#define NGRID 10000
#define NEARZERO 1e-5f

// One thread per (grid, mul) chain. m = tid & 15, g = tid >> 4.
// All 5 states + 16 scaled params live in registers; 365-step serial loop.
// q = mean over the 16 mul-members via shfl_xor within 16-lane groups.
// All inputs/outputs are float32 (jax default dtype).

__device__ __forceinline__ float fast_pow(float x, float y) {
    // x > 0 guaranteed by caller (SM >= NEARZERO, FC >= 50).
    return __expf(y * __logf(x));
}

__global__ __launch_bounds__(256) void hbv_kernel(
    const float* __restrict__ x,   // (NSTEP, NGRID, 3)  P,T,PET
    const float* __restrict__ pr,  // (NSTEP, NGRID, 3, NMUL) — only [-1] used
    const float* __restrict__ wl,  // (NGRID, 13, NMUL)
    const float* __restrict__ ac,  // (NGRID,)
    float* __restrict__ out)       // (NSTEP, NGRID)
{
    const int tid = blockIdx.x * blockDim.x + threadIdx.x;
    const int g = tid >> 4;
    const int m = tid & 15;
    if (g >= NGRID) return;

    // ---- HBV params from params_raw[NSTEP-1, g, i, m] ----
    const size_t pbase = ((size_t)(NSTEP - 1) * NGRID + (size_t)g) * 3 * NMUL + (size_t)m;
    const float parBETA   = 1.0f  + pr[pbase + 0 * NMUL] * 5.0f;
    const float parK0     = 0.05f + pr[pbase + 1 * NMUL] * 0.85f;
    const float parBETAET = 0.3f  + pr[pbase + 2 * NMUL] * 4.7f;

    // ---- Waterloss params from wl[g, i, m] ----
    const size_t wbase = (size_t)g * 13 * NMUL + (size_t)m;
    const float parFC    = 50.0f  + wl[wbase +  0 * NMUL] * 950.0f;
    const float parK1    = 0.01f  + wl[wbase +  1 * NMUL] * 0.49f;
    const float parK2    = 0.001f + wl[wbase +  2 * NMUL] * 0.199f;
    const float parLP    = 0.2f   + wl[wbase +  3 * NMUL] * 0.8f;
    const float parPERC  =          wl[wbase +  4 * NMUL] * 10.0f;
    const float parUZL   =          wl[wbase +  5 * NMUL] * 100.0f;
    const float parTT    = -2.5f  + wl[wbase +  6 * NMUL] * 5.0f;
    const float parCFMAX = 0.5f   + wl[wbase +  7 * NMUL] * 9.5f;
    const float parCFR   =          wl[wbase +  8 * NMUL] * 0.1f;
    const float parCWH   =          wl[wbase +  9 * NMUL] * 0.2f;
    const float parC     =          wl[wbase + 10 * NMUL] * 1.0f;
    const float parTR    =          wl[wbase + 11 * NMUL] * 20.0f;
    const float parAc    =          wl[wbase + 12 * NMUL] * 2500.0f;

    // ---- regional_flow (time-invariant) ----
    const float acm = ac[g];
    float regional_flow;
    if (acm < 2500.0f) {
        float rf = fminf(fmaxf((acm - parAc) * 0.001f, -1.0f), 1.0f);
        regional_flow = rf * parTR;
    } else {
        float e = fminf(fmaxf(-(acm - 2500.0f) * 0.02f, -10.0f), 0.0f);
        regional_flow = __expf(e) * parTR;
    }

    const float invFC   = 1.0f / parFC;
    const float invLPFC = 1.0f / (parLP * parFC);
    const float CFRCFMAX = parCFR * parCFMAX;

    float SNOWPACK = 0.001f, MELTWATER = 0.001f, SM = 0.001f, SUZ = 0.001f, SLZ = 0.001f;

    for (int t = 0; t < NSTEP; ++t) {
        const size_t xi = ((size_t)t * NGRID + (size_t)g) * 3;
        const float Pm   = x[xi + 0];
        const float Tm   = x[xi + 1];
        const float PETm = x[xi + 2];

        // snow routine
        const float warm = (Tm >= parTT) ? 1.0f : 0.0f;
        const float RAIN = Pm * warm;
        const float SNOW = Pm - RAIN;
        SNOWPACK += SNOW;
        const float melt = fminf(fmaxf(parCFMAX * (Tm - parTT), 0.0f), SNOWPACK);
        MELTWATER += melt;
        SNOWPACK  -= melt;
        const float refreezing = fminf(fmaxf(CFRCFMAX * (parTT - Tm), 0.0f), MELTWATER);
        SNOWPACK  += refreezing;
        MELTWATER -= refreezing;
        const float tosoil = fmaxf(MELTWATER - parCWH * SNOWPACK, 0.0f);
        MELTWATER -= tosoil;

        // soil routine
        const float soil_wetness = fminf(fmaxf(fast_pow(SM * invFC, parBETA), 0.0f), 1.0f);
        const float recharge = (RAIN + tosoil) * soil_wetness;
        SM = SM + RAIN + tosoil - recharge;
        const float excess = fmaxf(SM - parFC, 0.0f);
        SM -= excess;
        const float evapfactor = fminf(fmaxf(fast_pow(SM * invLPFC, parBETAET), 0.0f), 1.0f);
        const float ETact = fminf(SM, PETm * evapfactor);
        SM = fmaxf(SM - ETact, NEARZERO);
        const float capillary = fminf(SLZ, parC * SLZ * (1.0f - fminf(SM * invFC, 1.0f)));
        SM  = fmaxf(SM + capillary, NEARZERO);
        SLZ = fmaxf(SLZ - capillary, NEARZERO);

        // response routine
        SUZ = SUZ + recharge + excess;
        const float PERCa = fminf(SUZ, parPERC);
        SUZ -= PERCa;
        const float Q0 = parK0 * fmaxf(SUZ - parUZL, 0.0f);
        SUZ -= Q0;
        const float Q1 = parK1 * SUZ;
        SUZ -= Q1;
        SLZ += PERCa;
        SLZ = fmaxf(SLZ + regional_flow, 0.0f);
        const float Q2 = parK2 * SLZ;
        SLZ -= Q2;

        // mean over NMUL (16-lane subgroup reduction)
        float q = Q0 + Q1 + Q2;
        q += __shfl_xor(q, 1, 16);
        q += __shfl_xor(q, 2, 16);
        q += __shfl_xor(q, 4, 16);
        q += __shfl_xor(q, 8, 16);
        if (m == 0) {
            out[(size_t)t * NGRID + (size_t)g] = q * 0.0625f;
        }
    }
}

extern "C" void kernel_launch(void* const* d_in, const int* in_sizes, int n_in,
                              void* d_out, int out_size, void* d_ws, size_t ws_size,
                              hipStream_t stream) {
    const float* x  = (const float*)d_in[0];
    const float* pr = (const float*)d_in[1];
    const float* wl = (const float*)d_in[2];
    const float* ac = (const float*)d_in[3];
    float* out = (float*)d_out;

    const int total = NGRID * NMUL;            // 160,000 threads
    const int block = 256;
    const int grid = (total + block - 1) / block;  // 625 blocks
    hbv_kernel<<<grid, block, 0, stream>>>(x, pr, wl, ac, out);
}

// Round 3
// 947.582 us; speedup vs baseline: 1.0690x; 1.0690x over previous
//
#include <hip/hip_runtime.h>

#define NMUL 16
#define NSTEP 365
#define NGRID 10000
#define NEARZERO 1e-5f
#define UNROLL 4          // 365 = 4*91 + 1

// One thread per (grid, mul) chain; m = tid & 15, g = tid >> 4.
// Latency-bound regime (2.4 waves/SIMD): unroll t by 4, software-pipeline the
// forcing loads one body ahead, and run the 4 output shuffle-reductions as
// interleaved butterfly trees so no dependent chain sits exposed.

__device__ __forceinline__ float fast_pow(float x, float y) {
    // base > 0 guaranteed (SM >= NEARZERO, FC >= 50)
    return __expf(y * __logf(x));
}

struct HbvP {
    float parBETA, parK0, parBETAET;
    float parFC, parK1, parK2, parLP, parPERC, parUZL, parTT,
          parCFMAX, parCWH, parC;
    float invFC, invLPFC, CFRCFMAX, regional_flow;
};

__device__ __forceinline__ float hbv_step(
    float Pm, float Tm, float PETm,
    float& SNOWPACK, float& MELTWATER, float& SM, float& SUZ, float& SLZ,
    const HbvP& p)
{
    // snow routine
    const float RAIN = (Tm >= p.parTT) ? Pm : 0.0f;
    const float SNOW = Pm - RAIN;
    SNOWPACK += SNOW;
    const float melt = fminf(fmaxf(p.parCFMAX * (Tm - p.parTT), 0.0f), SNOWPACK);
    MELTWATER += melt;
    SNOWPACK  -= melt;
    const float refreezing = fminf(fmaxf(p.CFRCFMAX * (p.parTT - Tm), 0.0f), MELTWATER);
    SNOWPACK  += refreezing;
    MELTWATER -= refreezing;
    const float tosoil = fmaxf(MELTWATER - p.parCWH * SNOWPACK, 0.0f);
    MELTWATER -= tosoil;

    // soil routine
    const float soil_wetness = fminf(fast_pow(SM * p.invFC, p.parBETA), 1.0f);
    const float recharge = (RAIN + tosoil) * soil_wetness;
    SM = SM + RAIN + tosoil - recharge;
    const float excess = fmaxf(SM - p.parFC, 0.0f);
    SM -= excess;
    const float evapfactor = fminf(fast_pow(SM * p.invLPFC, p.parBETAET), 1.0f);
    const float ETact = fminf(SM, PETm * evapfactor);
    SM = fmaxf(SM - ETact, NEARZERO);
    const float capillary = fminf(SLZ, p.parC * SLZ * (1.0f - fminf(SM * p.invFC, 1.0f)));
    SM  = fmaxf(SM + capillary, NEARZERO);
    SLZ = fmaxf(SLZ - capillary, NEARZERO);

    // response routine
    SUZ = SUZ + recharge + excess;
    const float PERCa = fminf(SUZ, p.parPERC);
    SUZ -= PERCa;
    const float Q0 = p.parK0 * fmaxf(SUZ - p.parUZL, 0.0f);
    SUZ -= Q0;
    const float Q1 = p.parK1 * SUZ;
    SUZ -= Q1;
    SLZ += PERCa;
    SLZ = fmaxf(SLZ + p.regional_flow, 0.0f);
    const float Q2 = p.parK2 * SLZ;
    SLZ -= Q2;

    return Q0 + Q1 + Q2;
}

__global__ __launch_bounds__(256) void hbv_kernel(
    const float* __restrict__ x,   // (NSTEP, NGRID, 3)  P,T,PET
    const float* __restrict__ pr,  // (NSTEP, NGRID, 3, NMUL) — only [-1] used
    const float* __restrict__ wl,  // (NGRID, 13, NMUL)
    const float* __restrict__ ac,  // (NGRID,)
    float* __restrict__ out)       // (NSTEP, NGRID)
{
    const int tid = blockIdx.x * blockDim.x + threadIdx.x;  // grid*block == NGRID*NMUL exactly
    const int g = tid >> 4;
    const int m = tid & 15;

    HbvP p;
    // ---- HBV params from params_raw[NSTEP-1, g, i, m] ----
    const size_t pbase = ((size_t)(NSTEP - 1) * NGRID + (size_t)g) * 3 * NMUL + (size_t)m;
    p.parBETA   = 1.0f  + pr[pbase + 0 * NMUL] * 5.0f;
    p.parK0     = 0.05f + pr[pbase + 1 * NMUL] * 0.85f;
    p.parBETAET = 0.3f  + pr[pbase + 2 * NMUL] * 4.7f;

    // ---- Waterloss params from wl[g, i, m] ----
    const size_t wbase = (size_t)g * 13 * NMUL + (size_t)m;
    p.parFC    = 50.0f  + wl[wbase +  0 * NMUL] * 950.0f;
    p.parK1    = 0.01f  + wl[wbase +  1 * NMUL] * 0.49f;
    p.parK2    = 0.001f + wl[wbase +  2 * NMUL] * 0.199f;
    p.parLP    = 0.2f   + wl[wbase +  3 * NMUL] * 0.8f;
    p.parPERC  =          wl[wbase +  4 * NMUL] * 10.0f;
    p.parUZL   =          wl[wbase +  5 * NMUL] * 100.0f;
    p.parTT    = -2.5f  + wl[wbase +  6 * NMUL] * 5.0f;
    p.parCFMAX = 0.5f   + wl[wbase +  7 * NMUL] * 9.5f;
    const float parCFR =  wl[wbase +  8 * NMUL] * 0.1f;
    p.parCWH   =          wl[wbase +  9 * NMUL] * 0.2f;
    p.parC     =          wl[wbase + 10 * NMUL] * 1.0f;
    const float parTR  =  wl[wbase + 11 * NMUL] * 20.0f;
    const float parAc  =  wl[wbase + 12 * NMUL] * 2500.0f;

    // ---- regional_flow (time-invariant) ----
    const float acm = ac[g];
    if (acm < 2500.0f) {
        float rf = fminf(fmaxf((acm - parAc) * 0.001f, -1.0f), 1.0f);
        p.regional_flow = rf * parTR;
    } else {
        float e = fminf(fmaxf(-(acm - 2500.0f) * 0.02f, -10.0f), 0.0f);
        p.regional_flow = __expf(e) * parTR;
    }

    p.invFC    = 1.0f / p.parFC;
    p.invLPFC  = 1.0f / (p.parLP * p.parFC);
    p.CFRCFMAX = parCFR * p.parCFMAX;

    float SNOWPACK = 0.001f, MELTWATER = 0.001f, SM = 0.001f, SUZ = 0.001f, SLZ = 0.001f;

    // ---- software-pipelined main loop: 91 blocks of 4 steps + 1 tail ----
    float P0[UNROLL], T0[UNROLL], E0[UNROLL];
    #pragma unroll
    for (int u = 0; u < UNROLL; ++u) {
        const size_t xi = ((size_t)u * NGRID + (size_t)g) * 3;
        P0[u] = x[xi + 0]; T0[u] = x[xi + 1]; E0[u] = x[xi + 2];
    }

    int t = 0;
    for (int blk = 0; blk < 91; ++blk) {
        float P1[UNROLL], T1[UNROLL], E1[UNROLL];
        const int tn = t + UNROLL;
        if (blk < 90) {   // prefetch next body's forcing — consumed a full body later
            #pragma unroll
            for (int u = 0; u < UNROLL; ++u) {
                const size_t xi = ((size_t)(tn + u) * NGRID + (size_t)g) * 3;
                P1[u] = x[xi + 0]; T1[u] = x[xi + 1]; E1[u] = x[xi + 2];
            }
        } else {
            #pragma unroll
            for (int u = 0; u < UNROLL; ++u) { P1[u] = 0.f; T1[u] = 0.f; E1[u] = 0.f; }
        }

        float q[UNROLL];
        #pragma unroll
        for (int u = 0; u < UNROLL; ++u)
            q[u] = hbv_step(P0[u], T0[u], E0[u], SNOWPACK, MELTWATER, SM, SUZ, SLZ, p);

        // 4 interleaved butterfly trees (independent shuffles per latency step)
        #pragma unroll
        for (int s = 1; s < 16; s <<= 1) {
            #pragma unroll
            for (int u = 0; u < UNROLL; ++u)
                q[u] += __shfl_xor(q[u], s, 16);
        }
        if (m == 0) {
            #pragma unroll
            for (int u = 0; u < UNROLL; ++u)
                out[(size_t)(t + u) * NGRID + (size_t)g] = q[u] * 0.0625f;
        }

        #pragma unroll
        for (int u = 0; u < UNROLL; ++u) { P0[u] = P1[u]; T0[u] = T1[u]; E0[u] = E1[u]; }
        t = tn;
    }

    // tail: t = 364
    {
        const size_t xi = ((size_t)(NSTEP - 1) * NGRID + (size_t)g) * 3;
        float q = hbv_step(x[xi + 0], x[xi + 1], x[xi + 2],
                           SNOWPACK, MELTWATER, SM, SUZ, SLZ, p);
        #pragma unroll
        for (int s = 1; s < 16; s <<= 1) q += __shfl_xor(q, s, 16);
        if (m == 0) out[(size_t)(NSTEP - 1) * NGRID + (size_t)g] = q * 0.0625f;
    }
}

extern "C" void kernel_launch(void* const* d_in, const int* in_sizes, int n_in,
                              void* d_out, int out_size, void* d_ws, size_t ws_size,
                              hipStream_t stream) {
    const float* x  = (const float*)d_in[0];
    const float* pr = (const float*)d_in[1];
    const float* wl = (const float*)d_in[2];
    const float* ac = (const float*)d_in[3];
    float* out = (float*)d_out;

    const int total = NGRID * NMUL;            // 160,000 threads
    const int block = 256;
    const int grid = (total + block - 1) / block;  // 625 blocks, exact
    hbv_kernel<<<grid, block, 0, stream>>>(x, pr, wl, ac, out);
}